// Round 1
// baseline (1573.276 us; speedup 1.0000x reference)
//
#include <hip/hip_runtime.h>

// ---------------- problem constants ----------------
#define T_TOKENS 8192
#define H_DIM    2048
#define I_DIM    4096
#define NE       8
#define NPAIR    16384                 // T_TOKENS * TOP_K
#define BM       128
#define BN       128
#define BK       32
#define PADP     (NPAIR + NE * BM)     // 17408 rows (each expert segment padded to BM)
#define RT_MAX   (PADP / BM)           // 136 max row tiles

// ---------------- workspace layout (bytes) ----------------
// x_bf16   : T*H*2            =  33,554,432
// w_bf16   : NE*I*H*2         = 134,217,728  (shared: up before GEMM1, down before GEMM2)
// h_bf16   : PADP*I*2         = 142,606,336
// tok_id   : PADP*4
// pair_w   : PADP*4
// meta     : 128 B  ([0..7]=counts, [8..15]=cursor, [16..24]=padded starts)
// total ~ 310.6 MB
#define WS_X    0ull
#define WS_W    (WS_X + (size_t)T_TOKENS * H_DIM * 2)
#define WS_H    (WS_W + (size_t)NE * I_DIM * H_DIM * 2)
#define WS_TOK  (WS_H + (size_t)PADP * I_DIM * 2)
#define WS_PW   (WS_TOK + (size_t)PADP * 4)
#define WS_META (WS_PW + (size_t)PADP * 4)

typedef __attribute__((ext_vector_type(8))) short bf16x8;   // 8 bf16 = 4 VGPRs
typedef __attribute__((ext_vector_type(4))) float f32x4;    // MFMA C/D

__device__ __forceinline__ unsigned short f2bf(float f) {
  union { float f; unsigned u; } a; a.f = f;
  unsigned r = a.u + 0x7fffu + ((a.u >> 16) & 1u);   // RNE
  return (unsigned short)(r >> 16);
}

__device__ __forceinline__ void gload16(const void* g, void* l) {
  __builtin_amdgcn_global_load_lds(
      (const __attribute__((address_space(1))) unsigned int*)g,
      (__attribute__((address_space(3))) unsigned int*)l,
      16, 0, 0);
}

// ---------------- fp32 -> bf16 conversion (vectorized, grid-stride) ----------------
__global__ void cvt_f32_bf16(const float* __restrict__ in,
                             unsigned short* __restrict__ out, int n4) {
  int i = blockIdx.x * blockDim.x + threadIdx.x;
  int stride = gridDim.x * blockDim.x;
  for (; i < n4; i += stride) {
    float4 v = ((const float4*)in)[i];
    ushort4 o;
    o.x = f2bf(v.x); o.y = f2bf(v.y); o.z = f2bf(v.z); o.w = f2bf(v.w);
    ((ushort4*)out)[i] = o;
  }
}

// ---------------- routing: count / scan / scatter ----------------
__global__ void route_count(const int* __restrict__ idx, int* __restrict__ meta) {
  int i = blockIdx.x * blockDim.x + threadIdx.x;
  if (i < NPAIR) atomicAdd(&meta[idx[i]], 1);
}

__global__ void route_scan(int* __restrict__ meta) {
  if (threadIdx.x == 0 && blockIdx.x == 0) {
    int off = 0;
    for (int e = 0; e < NE; ++e) {
      meta[16 + e] = off;
      int c = meta[e];
      off += ((c + BM - 1) / BM) * BM;
    }
    meta[16 + NE] = off;   // total padded rows
  }
}

__global__ void route_scatter(const int* __restrict__ idx, const float* __restrict__ w,
                              int* __restrict__ meta, int* __restrict__ tok,
                              float* __restrict__ pw) {
  int i = blockIdx.x * blockDim.x + threadIdx.x;
  if (i < NPAIR) {
    int e = idx[i];
    int pos = meta[16 + e] + atomicAdd(&meta[8 + e], 1);
    tok[pos] = i >> 1;     // token id (TOP_K = 2)
    pw[pos]  = w[i];
  }
}

// ---------------- grouped GEMM1: h = relu2(x_gather @ up[e]^T), bf16 out ----------------
// BT layout; LDS tiles stored k-chunk-major [BK/8][128][8] to keep bank aliasing ~2-way.
__global__ __launch_bounds__(256) void gemm_up(
    const unsigned short* __restrict__ X, const unsigned short* __restrict__ W,
    unsigned short* __restrict__ Hb, const int* __restrict__ meta,
    const int* __restrict__ tok) {
  __shared__ unsigned short ldsA[BM * BK];   // 8 KB
  __shared__ unsigned short ldsB[BN * BK];   // 8 KB
  const int* pstart = meta + 16;
  const int NT = I_DIM / BN;                 // 32
  int rt = blockIdx.x / NT, nt = blockIdx.x % NT;
  int row0 = rt * BM;
  if (row0 >= pstart[NE]) return;
  int e = 0;
  #pragma unroll
  for (int q = 1; q < NE; ++q) if (row0 >= pstart[q]) e = q;

  int tid = threadIdx.x;
  int wv = tid >> 6, lane = tid & 63;
  int rowIdx = tid & 127;                    // staged row within tile
  int hiB = tid >> 7;                        // 0/1: k-subchunk within issue

  int tokA = tok[row0 + rowIdx]; if (tokA < 0) tokA = 0;   // pad rows read row 0
  const unsigned short* ap = X + (size_t)tokA * H_DIM + hiB * 8;
  const unsigned short* bp = W + (size_t)e * I_DIM * H_DIM
                               + (size_t)(nt * BN + rowIdx) * H_DIM + hiB * 8;
  char* la = (char*)ldsA + wv * 1024;
  char* lb = (char*)ldsB + wv * 1024;

  int wm = wv >> 1, wn = wv & 1;
  int arow0 = wm * 64 + (lane & 15);
  int brow0 = wn * 64 + (lane & 15);
  int hi = lane >> 4;

  f32x4 acc[4][4] = {};

  for (int kt = 0; kt < H_DIM / BK; ++kt) {
    const unsigned short* a0 = ap + kt * BK;
    const unsigned short* b0 = bp + kt * BK;
    gload16(a0,      la);
    gload16(a0 + 16, la + 4096);
    gload16(b0,      lb);
    gload16(b0 + 16, lb + 4096);
    __syncthreads();
    bf16x8 af[4], bfr[4];
    #pragma unroll
    for (int f = 0; f < 4; ++f) {
      af[f]  = *(const bf16x8*)(ldsA + hi * 1024 + (arow0 + f * 16) * 8);
      bfr[f] = *(const bf16x8*)(ldsB + hi * 1024 + (brow0 + f * 16) * 8);
    }
    #pragma unroll
    for (int fm = 0; fm < 4; ++fm)
      #pragma unroll
      for (int fn = 0; fn < 4; ++fn)
        acc[fm][fn] = __builtin_amdgcn_mfma_f32_16x16x32_bf16(af[fm], bfr[fn], acc[fm][fn], 0, 0, 0);
    __syncthreads();
  }

  // epilogue: relu2 -> bf16 -> store (pad rows store garbage-but-finite; discarded later)
  int crow = wm * 64 + ((lane >> 4) << 2);
  int ccol = nt * BN + wn * 64 + (lane & 15);
  #pragma unroll
  for (int fm = 0; fm < 4; ++fm) {
    #pragma unroll
    for (int j = 0; j < 4; ++j) {
      int p = row0 + crow + fm * 16 + j;
      unsigned short* dst = Hb + (size_t)p * I_DIM + ccol;
      #pragma unroll
      for (int fn = 0; fn < 4; ++fn) {
        float v = acc[fm][fn][j];
        v = v > 0.f ? v * v : 0.f;
        dst[fn * 16] = f2bf(v);
      }
    }
  }
}

// ---------------- grouped GEMM2: out[tok] += w * (h @ down[e]^T) ----------------
__global__ __launch_bounds__(256) void gemm_down(
    const unsigned short* __restrict__ Hb, const unsigned short* __restrict__ W,
    float* __restrict__ out, const int* __restrict__ meta,
    const int* __restrict__ tok, const float* __restrict__ pw) {
  __shared__ unsigned short ldsA[BM * BK];
  __shared__ unsigned short ldsB[BN * BK];
  const int* pstart = meta + 16;
  const int NT = H_DIM / BN;                 // 16
  int rt = blockIdx.x / NT, nt = blockIdx.x % NT;
  int row0 = rt * BM;
  if (row0 >= pstart[NE]) return;
  int e = 0;
  #pragma unroll
  for (int q = 1; q < NE; ++q) if (row0 >= pstart[q]) e = q;

  int tid = threadIdx.x;
  int wv = tid >> 6, lane = tid & 63;
  int rowIdx = tid & 127;
  int hiB = tid >> 7;

  const unsigned short* ap = Hb + (size_t)(row0 + rowIdx) * I_DIM + hiB * 8;
  const unsigned short* bp = W + (size_t)e * H_DIM * I_DIM
                               + (size_t)(nt * BN + rowIdx) * I_DIM + hiB * 8;
  char* la = (char*)ldsA + wv * 1024;
  char* lb = (char*)ldsB + wv * 1024;

  int wm = wv >> 1, wn = wv & 1;
  int arow0 = wm * 64 + (lane & 15);
  int brow0 = wn * 64 + (lane & 15);
  int hi = lane >> 4;

  f32x4 acc[4][4] = {};

  for (int kt = 0; kt < I_DIM / BK; ++kt) {
    const unsigned short* a0 = ap + kt * BK;
    const unsigned short* b0 = bp + kt * BK;
    gload16(a0,      la);
    gload16(a0 + 16, la + 4096);
    gload16(b0,      lb);
    gload16(b0 + 16, lb + 4096);
    __syncthreads();
    bf16x8 af[4], bfr[4];
    #pragma unroll
    for (int f = 0; f < 4; ++f) {
      af[f]  = *(const bf16x8*)(ldsA + hi * 1024 + (arow0 + f * 16) * 8);
      bfr[f] = *(const bf16x8*)(ldsB + hi * 1024 + (brow0 + f * 16) * 8);
    }
    #pragma unroll
    for (int fm = 0; fm < 4; ++fm)
      #pragma unroll
      for (int fn = 0; fn < 4; ++fn)
        acc[fm][fn] = __builtin_amdgcn_mfma_f32_16x16x32_bf16(af[fm], bfr[fn], acc[fm][fn], 0, 0, 0);
    __syncthreads();
  }

  int crow = wm * 64 + ((lane >> 4) << 2);
  int ccol = nt * BN + wn * 64 + (lane & 15);
  #pragma unroll
  for (int fm = 0; fm < 4; ++fm) {
    #pragma unroll
    for (int j = 0; j < 4; ++j) {
      int p = row0 + crow + fm * 16 + j;
      int t = tok[p];
      if (t < 0) continue;                   // padding row
      float wgt = pw[p];
      float* dst = out + (size_t)t * H_DIM + ccol;
      #pragma unroll
      for (int fn = 0; fn < 4; ++fn)
        atomicAdd(dst + fn * 16, wgt * acc[fm][fn][j]);
    }
  }
}

// ---------------- launch ----------------
extern "C" void kernel_launch(void* const* d_in, const int* in_sizes, int n_in,
                              void* d_out, int out_size, void* d_ws, size_t ws_size,
                              hipStream_t stream) {
  const float* x   = (const float*)d_in[0];
  const int*   tki = (const int*)d_in[1];
  const float* tkw = (const float*)d_in[2];
  const float* up  = (const float*)d_in[3];
  const float* dn  = (const float*)d_in[4];
  float* out = (float*)d_out;
  char* ws = (char*)d_ws;

  unsigned short* xb  = (unsigned short*)(ws + WS_X);
  unsigned short* wb  = (unsigned short*)(ws + WS_W);
  unsigned short* hb  = (unsigned short*)(ws + WS_H);
  int*            tok = (int*)(ws + WS_TOK);
  float*          pw  = (float*)(ws + WS_PW);
  int*            meta= (int*)(ws + WS_META);

  hipMemsetAsync(d_out, 0, (size_t)out_size * sizeof(float), stream);
  hipMemsetAsync(meta, 0, 128, stream);
  hipMemsetAsync(tok, 0xFF, (size_t)PADP * 4, stream);    // -1 = padding

  cvt_f32_bf16<<<2048, 256, 0, stream>>>(x, xb, T_TOKENS * H_DIM / 4);
  cvt_f32_bf16<<<4096, 256, 0, stream>>>(up, wb, NE * I_DIM * H_DIM / 4);

  route_count  <<<NPAIR / 256, 256, 0, stream>>>(tki, meta);
  route_scan   <<<1, 64, 0, stream>>>(meta);
  route_scatter<<<NPAIR / 256, 256, 0, stream>>>(tki, tkw, meta, tok, pw);

  gemm_up<<<RT_MAX * (I_DIM / BN), 256, 0, stream>>>(xb, wb, hb, meta, tok);

  cvt_f32_bf16<<<4096, 256, 0, stream>>>(dn, wb, NE * H_DIM * I_DIM / 4);

  gemm_down<<<RT_MAX * (H_DIM / BN), 256, 0, stream>>>(hb, wb, out, meta, tok, pw);
}